// Round 2
// baseline (393.184 us; speedup 1.0000x reference)
//
#include <hip/hip_runtime.h>

// B=32, T=512, D=512, L=2048. x:(B,T,D) f32, durations:(B,T) f32.
// Outputs concatenated in d_out: aligned (B,L,D) f32 then attn (B,T,L) f32.
//
// Structure: attn column l is a softmax over tokens of -0.2*(l-start_t)^2.
// Only tokens with exponent within ~40 of the max contribute above 1e-17,
// so the aligned gather-FMA runs over a narrow band; attn itself is written
// densely (exp underflows to 0.0 outside the band), which replaces a
// separate memset pass and keeps writes line-coalesced within one block.

static constexpr int Bc = 32;
static constexpr int Tc = 512;
static constexpr int Dc = 512;
static constexpr int Lc = 2048;
static constexpr int LT = 16;            // frames per block
static constexpr float SIGMA = 0.2f;

// Kernel 1: starts[b][t] = exclusive cumsum of durations along t.
__global__ void cumsum_starts(const float* __restrict__ dur,
                              float* __restrict__ starts) {
  const int b = blockIdx.x;
  const int t = threadIdx.x; // blockDim.x == Tc
  __shared__ float buf[Tc];
  float d = dur[(size_t)b * Tc + t];
  float v = d;
  buf[t] = v;
  __syncthreads();
  for (int off = 1; off < Tc; off <<= 1) {
    float add = (t >= off) ? buf[t - off] : 0.0f;
    __syncthreads();
    v += add;
    buf[t] = v;
    __syncthreads();
  }
  starts[(size_t)b * Tc + t] = v - d;
}

// Kernel 2: one 256-thread block per (b, 16-frame tile).
__global__ void __launch_bounds__(256)
soft_align(const float* __restrict__ x,
           const float* __restrict__ starts,
           float* __restrict__ aligned,
           float* __restrict__ attn) {
  const int tid = threadIdx.x;
  const int b = blockIdx.x >> 7;            // / (Lc/LT = 128)
  const int tile = blockIdx.x & 127;
  const int l0 = tile * LT;

  __shared__ float sbS[Tc];                 // token start offsets
  __shared__ float negamS[LT];              // SIGMA*smin^2 per l (= -max exponent)
  __shared__ float invS[LT];                // 1/denom per l
  __shared__ float dred[LT][17];            // denom partials [l][chunk]
  __shared__ int T0s, T1s;                  // tile-wide significant band

  if (tid == 0) { T0s = Tc; T1s = 0; }
  sbS[tid]       = starts[(size_t)b * Tc + tid];
  sbS[tid + 256] = starts[(size_t)b * Tc + tid + 256];
  __syncthreads();

  // per-l exact softmax max: nearest start to frame l (starts nondecreasing)
  if (tid < LT) {
    const float fl = (float)(l0 + tid);
    int lo = 0, hi = Tc;
    while (lo < hi) { int mid = (lo + hi) >> 1; if (sbS[mid] <= fl) lo = mid + 1; else hi = mid; }
    // sbS[0]=0 <= fl always -> lo >= 1
    float smin = fl - sbS[lo - 1];
    if (lo < Tc) smin = fminf(smin, sbS[lo] - fl);
    negamS[tid] = SIGMA * smin * smin;
  }
  __syncthreads();

  // full-T scan: exact denominator + significant band bounds.
  // thread = (lg = which l, inner = token sub-chunk); t strided by 16 to
  // keep sbS reads broadcast-friendly (16 banks, 4 lanes each).
  {
    const int lg = tid >> 4, inner = tid & 15;
    const float fl = (float)(l0 + lg);
    const float negam = negamS[lg];
    float partial = 0.0f;
    int tmn = Tc, tmx = -1;
    for (int k = 0; k < Tc / 16; ++k) {
      const int t = inner + 16 * k;
      const float s = fl - sbS[t];
      const float e = __expf(negam - SIGMA * s * s); // <= 1, max term = 1
      partial += e;
      if (e > 1e-18f) { tmn = min(tmn, t); tmx = max(tmx, t); }
    }
    dred[lg][inner] = partial;
    if (tmx >= 0) { atomicMin(&T0s, tmn); atomicMax(&T1s, tmx + 1); }
  }
  __syncthreads();
  if (tid < LT) {
    float denom = 0.0f;
    #pragma unroll
    for (int k = 0; k < 16; ++k) denom += dred[tid][k];
    invS[tid] = 1.0f / denom;              // denom >= 1 (max term included)
  }
  __syncthreads();

  const int T0 = T0s, T1 = T1s;

  // Phase B: aligned[b][l][:] = sum_t w(t,l)/denom * x[b][t][:], band only.
  {
    const int lg = tid >> 4, dpart = tid & 15; // 16 l x 16 d-slots (float4)
    const float fl = (float)(l0 + lg);
    const float negam = negamS[lg];
    const float4* __restrict__ xb = (const float4*)(x + (size_t)b * Tc * Dc);
    float4 acc[8] = {};
    for (int t = T0; t < T1; ++t) {
      const float s = fl - sbS[t];
      const float w = __expf(negam - SIGMA * s * s);
      const float4* __restrict__ row = xb + (size_t)t * (Dc / 4) + dpart;
      #pragma unroll
      for (int j = 0; j < 8; ++j) {
        const float4 xv = row[16 * j];
        acc[j].x += w * xv.x; acc[j].y += w * xv.y;
        acc[j].z += w * xv.z; acc[j].w += w * xv.w;
      }
    }
    const float inv = invS[lg];
    float4* __restrict__ ab = (float4*)(aligned + ((size_t)b * Lc + l0 + lg) * Dc);
    #pragma unroll
    for (int j = 0; j < 8; ++j) {
      float4 v = acc[j];
      v.x *= inv; v.y *= inv; v.z *= inv; v.w *= inv;
      ab[dpart + 16 * j] = v;              // 16 consecutive float4 per l-row
    }
  }

  // Phase C: dense attn write (zeros via expf underflow), coalesced:
  // 16 consecutive threads cover 16 consecutive l (one 64B line).
  {
    const int tg = tid >> 4, ll = tid & 15;
    const float fl = (float)(l0 + ll);
    const float negam = negamS[ll];
    const float inv = invS[ll];
    float* __restrict__ ap = attn + (size_t)b * Tc * Lc + l0 + ll;
    #pragma unroll 4
    for (int pass = 0; pass < Tc / 16; ++pass) {
      const int t = pass * 16 + tg;
      const float s = fl - sbS[t];
      ap[(size_t)t * Lc] = __expf(negam - SIGMA * s * s) * inv;
    }
  }
}

extern "C" void kernel_launch(void* const* d_in, const int* in_sizes, int n_in,
                              void* d_out, int out_size, void* d_ws, size_t ws_size,
                              hipStream_t stream) {
  const float* x   = (const float*)d_in[0];
  const float* dur = (const float*)d_in[1];

  float* aligned = (float*)d_out;                        // B*L*D
  float* attn    = (float*)d_out + (size_t)Bc * Lc * Dc; // B*T*L
  float* starts  = (float*)d_ws;                         // B*T

  cumsum_starts<<<Bc, Tc, 0, stream>>>(dur, starts);
  soft_align<<<Bc * (Lc / LT), 256, 0, stream>>>(x, starts, aligned, attn);
}

// Round 4
// 328.335 us; speedup vs baseline: 1.1975x; 1.1975x over previous
//
#include <hip/hip_runtime.h>

// B=32, T=512, D=512, L=2048. x:(B,T,D) f32, durations:(B,T) f32.
// d_out = aligned (B,L,D) f32  ||  attn (B,T,L) f32.
//
// attn column l = softmax_t of -0.2*(l-start_t)^2. Only tokens within
// sqrt(smin^2+200) of frame l contribute > 1e-17 of the max term, so the
// aligned gather runs over a narrow per-wave band. attn is written densely
// (exp underflow -> 0), replacing a memset pass.
//
// Layout (R3/R4): 64 frames per block so every attn store is a full
// 128B-line write (wave writes 256B contiguous along l, tile segments are
// 256B-aligned and block-owned -> no cross-XCD partial-line sharing).
// Bands stay per-wave (16 frames) so banded-FMA waste doesn't grow.
// Nontemporal stores for both output streams (never re-read).

typedef float v4f __attribute__((ext_vector_type(4))); // native vec for NT stores

static constexpr int Bc = 32;
static constexpr int Tc = 512;
static constexpr int Dc = 512;
static constexpr int Lc = 2048;
static constexpr int LT = 64;             // frames per block
static constexpr float SIGMA = 0.2f;

// Kernel 1: starts[b][t] = exclusive cumsum of durations along t.
__global__ void cumsum_starts(const float* __restrict__ dur,
                              float* __restrict__ starts) {
  const int b = blockIdx.x;
  const int t = threadIdx.x; // blockDim.x == Tc
  __shared__ float buf[Tc];
  float d = dur[(size_t)b * Tc + t];
  float v = d;
  buf[t] = v;
  __syncthreads();
  for (int off = 1; off < Tc; off <<= 1) {
    float add = (t >= off) ? buf[t - off] : 0.0f;
    __syncthreads();
    v += add;
    buf[t] = v;
    __syncthreads();
  }
  starts[(size_t)b * Tc + t] = v - d;
}

// Kernel 2: one 256-thread block per (b, 64-frame tile).
__global__ void __launch_bounds__(256)
soft_align(const float* __restrict__ x,
           const float* __restrict__ starts,
           float* __restrict__ aligned,
           float* __restrict__ attn) {
  const int tid = threadIdx.x;
  const int b = blockIdx.x >> 5;            // / (Lc/LT = 32)
  const int tile = blockIdx.x & 31;
  const int l0 = tile * LT;

  __shared__ float sbS[Tc];                 // token start offsets
  __shared__ float negamS[LT];              // SIGMA*smin^2 per l
  __shared__ float invS[LT];                // 1/denom per l
  __shared__ float dred[LT][4];             // denom partials
  __shared__ int T0w[4], T1w[4];            // per-wave significant band

  if (tid < 4) { T0w[tid] = Tc; T1w[tid] = 0; }
  sbS[tid]       = starts[(size_t)b * Tc + tid];
  sbS[tid + 256] = starts[(size_t)b * Tc + tid + 256];
  __syncthreads();

  // exact per-l softmax max: nearest start (starts nondecreasing, sbS[0]=0)
  if (tid < LT) {
    const float fl = (float)(l0 + tid);
    int lo = 0, hi = Tc;
    while (lo < hi) { int mid = (lo + hi) >> 1; if (sbS[mid] <= fl) lo = mid + 1; else hi = mid; }
    float smin = fl - sbS[lo - 1];          // lo >= 1 always
    if (lo < Tc) smin = fminf(smin, sbS[lo] - fl);
    negamS[tid] = SIGMA * smin * smin;
  }
  __syncthreads();

  // Phase A: full-T exact denominators + per-wave band bounds.
  // thread = (lg = l index 0..63, inner = t sub-chunk 0..3); wave w = tid>>6
  // covers l in [16w, 16w+16) -- matches Phase B's wave->l assignment.
  {
    const int lg = tid >> 2, inner = tid & 3, w = tid >> 6;
    const float fl = (float)(l0 + lg);
    const float negam = negamS[lg];
    float partial = 0.0f;
    int tmn = Tc, tmx = -1;
    for (int k = 0; k < Tc / 4; ++k) {
      const int t = inner + 4 * k;
      const float s = fl - sbS[t];
      const float e = __expf(negam - SIGMA * s * s); // <= 1, max term = 1
      partial += e;
      if (e > 1e-18f) { tmn = min(tmn, t); tmx = max(tmx, t); }
    }
    dred[lg][inner] = partial;
    if (tmx >= 0) { atomicMin(&T0w[w], tmn); atomicMax(&T1w[w], tmx + 1); }
  }
  __syncthreads();
  if (tid < LT) {
    invS[tid] = 1.0f / (dred[tid][0] + dred[tid][1] + dred[tid][2] + dred[tid][3]);
  }
  __syncthreads();

  // Phase B: aligned[b][l][:] = sum_t w/denom * x[b][t][:], per-wave band.
  {
    const int w = tid >> 6;
    const int lane = tid & 63;
    const int lgw = lane >> 4;              // 0..3
    const int dpart = lane & 15;            // 0..15 (float4 slot)
    const int Tb0 = T0w[w], Tb1 = T1w[w];
    const float4* __restrict__ xb = (const float4*)(x + (size_t)b * Tc * Dc);
    for (int o = 0; o < 4; ++o) {
      const int lr = 16 * w + 4 * lgw + o;  // wave's 16 l, bijective
      const float fl = (float)(l0 + lr);
      const float negam = negamS[lr];
      float4 acc[8] = {};
      for (int t = Tb0; t < Tb1; ++t) {
        const float s = fl - sbS[t];
        const float wgt = __expf(negam - SIGMA * s * s);
        const float4* __restrict__ row = xb + (size_t)t * (Dc / 4) + dpart;
        #pragma unroll
        for (int j = 0; j < 8; ++j) {
          const float4 xv = row[16 * j];
          acc[j].x += wgt * xv.x; acc[j].y += wgt * xv.y;
          acc[j].z += wgt * xv.z; acc[j].w += wgt * xv.w;
        }
      }
      const float inv = invS[lr];
      v4f* __restrict__ ab = (v4f*)(aligned + ((size_t)b * Lc + l0 + lr) * Dc);
      #pragma unroll
      for (int j = 0; j < 8; ++j) {
        v4f v = { acc[j].x * inv, acc[j].y * inv, acc[j].z * inv, acc[j].w * inv };
        __builtin_nontemporal_store(v, ab + dpart + 16 * j); // 256B/row chunks
      }
    }
  }

  // Phase C: dense attn write. Wave = 64 consecutive l for one t ->
  // 256B contiguous store = two full 128B lines, tile-owned (l0 % 64 == 0).
  {
    const int ll = tid & 63;
    const int tg = tid >> 6;                // 0..3
    const float fl = (float)(l0 + ll);
    const float negam = negamS[ll];
    const float inv = invS[ll];
    float* __restrict__ ap = attn + (size_t)b * Tc * Lc + l0 + ll;
    for (int pass = 0; pass < Tc / 4; ++pass) {
      const int t = pass * 4 + tg;
      const float s = fl - sbS[t];
      __builtin_nontemporal_store(__expf(negam - SIGMA * s * s) * inv,
                                  ap + (size_t)t * Lc);
    }
  }
}

extern "C" void kernel_launch(void* const* d_in, const int* in_sizes, int n_in,
                              void* d_out, int out_size, void* d_ws, size_t ws_size,
                              hipStream_t stream) {
  const float* x   = (const float*)d_in[0];
  const float* dur = (const float*)d_in[1];

  float* aligned = (float*)d_out;                        // B*L*D
  float* attn    = (float*)d_out + (size_t)Bc * Lc * Dc; // B*T*L
  float* starts  = (float*)d_ws;                         // B*T

  cumsum_starts<<<Bc, Tc, 0, stream>>>(dur, starts);
  soft_align<<<Bc * (Lc / LT), 256, 0, stream>>>(x, starts, aligned, attn);
}

// Round 5
// 304.435 us; speedup vs baseline: 1.2915x; 1.0785x over previous
//
#include <hip/hip_runtime.h>

// B=32, T=512, D=512, L=2048. x:(B,T,D) f32, durations:(B,T) f32.
// d_out = aligned (B,L,D) f32  ||  attn (B,T,L) f32.
//
// attn column l = softmax_t of -0.2*(l-start_t)^2. Terms more than
// sqrt(smin^2+200) frames from l are < e^-40 of the max term (denom >= 1),
// i.e. < 4.3e-18 -> exact 0 in fp32 outputs and invisible in the denom.
// So: per-l band by binary search; banded denom; banded gather for aligned;
// dense attn write with literal zeros outside the band.
//
// R5: Phase B walks the wave's 16-l union band ONCE with fully-distinct
// per-lane row addresses (64 lanes x 16B = full coalescing; previously 4-way
// duplicated addresses at 1/4 request efficiency, re-walked 4x).

typedef float v4f __attribute__((ext_vector_type(4)));

static constexpr int Bc = 32;
static constexpr int Tc = 512;
static constexpr int Dc = 512;
static constexpr int Lc = 2048;
static constexpr int LT = 64;             // frames per block
static constexpr float SIGMA = 0.2f;
static constexpr float CUT2 = 200.0f;     // 40/SIGMA

// Kernel 1: starts[b][t] = exclusive cumsum of durations along t.
__global__ void cumsum_starts(const float* __restrict__ dur,
                              float* __restrict__ starts) {
  const int b = blockIdx.x;
  const int t = threadIdx.x; // blockDim.x == Tc
  __shared__ float buf[Tc];
  float d = dur[(size_t)b * Tc + t];
  float v = d;
  buf[t] = v;
  __syncthreads();
  for (int off = 1; off < Tc; off <<= 1) {
    float add = (t >= off) ? buf[t - off] : 0.0f;
    __syncthreads();
    v += add;
    buf[t] = v;
    __syncthreads();
  }
  starts[(size_t)b * Tc + t] = v - d;
}

// Kernel 2: one 256-thread block per (b, 64-frame tile).
__global__ void __launch_bounds__(256)
soft_align(const float* __restrict__ x,
           const float* __restrict__ starts,
           float* __restrict__ aligned,
           float* __restrict__ attn) {
  const int tid = threadIdx.x;
  const int b = blockIdx.x >> 5;            // / (Lc/LT = 32)
  const int tile = blockIdx.x & 31;
  const int l0 = tile * LT;

  __shared__ float sbS[Tc];                 // token start offsets
  __shared__ float negamS[LT];              // SIGMA*smin^2 per l
  __shared__ float invS[LT];                // 1/denom per l
  __shared__ float dred[LT][4];             // denom partials
  __shared__ int bt0S[LT], bt1S[LT];        // per-l significant band
  __shared__ int T0w[4], T1w[4];            // per-wave union band

  if (tid < 4) { T0w[tid] = Tc; T1w[tid] = 0; }
  sbS[tid]       = starts[(size_t)b * Tc + tid];
  sbS[tid + 256] = starts[(size_t)b * Tc + tid + 256];
  __syncthreads();

  // Per-l: nearest start (exact softmax max) + band bounds, by binary search.
  if (tid < LT) {
    const float fl = (float)(l0 + tid);
    int lo = 0, hi = Tc;
    while (lo < hi) { int mid = (lo + hi) >> 1; if (sbS[mid] <= fl) lo = mid + 1; else hi = mid; }
    float smin = fl - sbS[lo - 1];          // sbS[0]=0 <= fl -> lo >= 1
    if (lo < Tc) smin = fminf(smin, sbS[lo] - fl);
    const float negam = SIGMA * smin * smin;
    negamS[tid] = negam;
    const float smax = sqrtf(smin * smin + CUT2);
    const float loV = fl - smax, hiV = fl + smax;
    // bt0 = first t with sbS[t] >= loV  (within [0, lo])
    int a = 0, c = lo;
    while (a < c) { int mid = (a + c) >> 1; if (sbS[mid] < loV) a = mid + 1; else c = mid; }
    const int bt0 = a;
    // bt1 = first t with sbS[t] > hiV   (within [lo, Tc])
    a = lo; c = Tc;
    while (a < c) { int mid = (a + c) >> 1; if (sbS[mid] <= hiV) a = mid + 1; else c = mid; }
    const int bt1 = a;                      // band nonempty (nearest inside)
    bt0S[tid] = bt0; bt1S[tid] = bt1;
    atomicMin(&T0w[tid >> 4], bt0);
    atomicMax(&T1w[tid >> 4], bt1);
  }
  __syncthreads();

  // Phase A: banded exact-in-fp32 denominators. 4 threads per l.
  {
    const int lg = tid >> 2, inner = tid & 3;
    const float fl = (float)(l0 + lg);
    const float negam = negamS[lg];
    float partial = 0.0f;
    const int e0 = bt0S[lg], e1 = bt1S[lg];
    for (int t = e0 + inner; t < e1; t += 4) {
      const float s = fl - sbS[t];
      partial += __expf(negam - SIGMA * s * s); // <= 1, max term = 1
    }
    dred[lg][inner] = partial;
  }
  __syncthreads();
  if (tid < LT) {
    invS[tid] = 1.0f / (dred[tid][0] + dred[tid][1] + dred[tid][2] + dred[tid][3]);
  }
  __syncthreads();

  // Phase B: aligned gather over the wave's union band, one pass.
  // Lane reads 2 distinct float4 of row t (full coalescing); 8 l per half.
  {
    const int w = tid >> 6;                 // wave id, covers l [16w,16w+16)
    const int lane = tid & 63;
    const int Tb0 = T0w[w], Tb1 = T1w[w];
    const float4* __restrict__ xb = (const float4*)(x + (size_t)b * Tc * Dc);
    for (int half = 0; half < 2; ++half) {
      const int lbase = 16 * w + 8 * half;
      float4 acc[8][2] = {};
      for (int t = Tb0; t < Tb1; ++t) {
        const float4 r0 = xb[(size_t)t * (Dc / 4) + lane];
        const float4 r1 = xb[(size_t)t * (Dc / 4) + 64 + lane];
        const float sb = sbS[t];
        #pragma unroll
        for (int li = 0; li < 8; ++li) {
          const float fl = (float)(l0 + lbase + li);
          const float s = fl - sb;
          const float wgt = __expf(negamS[lbase + li] - SIGMA * s * s);
          acc[li][0].x += wgt * r0.x; acc[li][0].y += wgt * r0.y;
          acc[li][0].z += wgt * r0.z; acc[li][0].w += wgt * r0.w;
          acc[li][1].x += wgt * r1.x; acc[li][1].y += wgt * r1.y;
          acc[li][1].z += wgt * r1.z; acc[li][1].w += wgt * r1.w;
        }
      }
      #pragma unroll
      for (int li = 0; li < 8; ++li) {
        const float inv = invS[lbase + li];
        v4f* __restrict__ ab =
            (v4f*)(aligned + ((size_t)b * Lc + l0 + lbase + li) * Dc);
        v4f v0 = { acc[li][0].x * inv, acc[li][0].y * inv,
                   acc[li][0].z * inv, acc[li][0].w * inv };
        v4f v1 = { acc[li][1].x * inv, acc[li][1].y * inv,
                   acc[li][1].z * inv, acc[li][1].w * inv };
        __builtin_nontemporal_store(v0, ab + lane);      // 1KB/instr, contiguous
        __builtin_nontemporal_store(v1, ab + 64 + lane);
      }
    }
  }

  // Phase C: dense attn write; literal zeros outside the per-l band.
  // Wave stores 64 consecutive l per t -> 256B contiguous (full lines).
  {
    const int ll = tid & 63;
    const int tg = tid >> 6;                // 0..3
    const float fl = (float)(l0 + ll);
    const float negam = negamS[ll];
    const float inv = invS[ll];
    const int e0 = bt0S[ll], e1 = bt1S[ll];
    float* __restrict__ ap = attn + (size_t)b * Tc * Lc + l0 + ll;
    for (int pass = 0; pass < Tc / 4; ++pass) {
      const int t = pass * 4 + tg;
      float val = 0.0f;
      if (t >= e0 && t < e1) {
        const float s = fl - sbS[t];
        val = __expf(negam - SIGMA * s * s) * inv;
      }
      __builtin_nontemporal_store(val, ap + (size_t)t * Lc);
    }
  }
}

extern "C" void kernel_launch(void* const* d_in, const int* in_sizes, int n_in,
                              void* d_out, int out_size, void* d_ws, size_t ws_size,
                              hipStream_t stream) {
  const float* x   = (const float*)d_in[0];
  const float* dur = (const float*)d_in[1];

  float* aligned = (float*)d_out;                        // B*L*D
  float* attn    = (float*)d_out + (size_t)Bc * Lc * Dc; // B*T*L
  float* starts  = (float*)d_ws;                         // B*T

  cumsum_starts<<<Bc, Tc, 0, stream>>>(dur, starts);
  soft_align<<<Bc * (Lc / LT), 256, 0, stream>>>(x, starts, aligned, attn);
}